// Round 2
// baseline (77.707 us; speedup 1.0000x reference)
//
#include <hip/hip_runtime.h>

// Problem constants
#define BB 32
#define CC 64
#define HH 128
#define WW 128
#define HWSZ (HH * WW)            // 16384
#define NSITES (BB * HWSZ)        // 524288
#define NWORDS (NSITES / 64)      // 8192

// ---------------------------------------------------------------------------
// Kernel 1: per-site activity flags, packed 64 sites per uint64 word.
// Block = 256 threads handles 1024 consecutive sites (4 sites/thread, float4).
// Grid = 512 blocks. All loads coalesced: for fixed c, a wave reads 1 KiB
// contiguous.
// ---------------------------------------------------------------------------
__global__ __launch_bounds__(256) void k_flags(const float* __restrict__ x,
                                               unsigned long long* __restrict__ flags) {
    const int t = threadIdx.x;
    const long long site0 = (long long)blockIdx.x * 1024 + 4 * t;  // 4 consecutive sites
    const int b = (int)(site0 >> 14);       // /HWSZ  (blocks never straddle b)
    const int hw = (int)(site0 & (HWSZ - 1));
    const float* p = x + ((size_t)b * CC) * HWSZ + hw;

    float a0 = 0.f, a1 = 0.f, a2 = 0.f, a3 = 0.f;
#pragma unroll 8
    for (int c = 0; c < CC; ++c) {
        const float4 v = *reinterpret_cast<const float4*>(p + (size_t)c * HWSZ);
        a0 += fabsf(v.x);
        a1 += fabsf(v.y);
        a2 += fabsf(v.z);
        a3 += fabsf(v.w);
    }
    unsigned int nib = (unsigned int)(a0 != 0.f) | ((unsigned int)(a1 != 0.f) << 1) |
                       ((unsigned int)(a2 != 0.f) << 2) | ((unsigned int)(a3 != 0.f) << 3);

    __shared__ unsigned int nibs[256];
    nibs[t] = nib;
    __syncthreads();
    if (t < 16) {
        unsigned long long w = 0ull;
#pragma unroll
        for (int j = 0; j < 16; ++j)
            w |= (unsigned long long)nibs[16 * t + j] << (4 * j);
        flags[(size_t)blockIdx.x * 16 + t] = w;
    }
}

// ---------------------------------------------------------------------------
// Kernel 2: exclusive scan of per-word popcounts. Single block, 1024 threads,
// 8 words/thread. Also writes total count (uint in ws, float at end of d_out).
// ---------------------------------------------------------------------------
__global__ __launch_bounds__(1024) void k_scan(const unsigned long long* __restrict__ flags,
                                               unsigned int* __restrict__ wordOffsets,
                                               unsigned int* __restrict__ countp,
                                               float* __restrict__ out_count_f) {
    __shared__ unsigned int sums[1024];
    const int t = threadIdx.x;
    unsigned int c[8];
    unsigned int s = 0;
#pragma unroll
    for (int j = 0; j < 8; ++j) {
        c[j] = (unsigned int)__popcll(flags[8 * t + j]);
        s += c[j];
    }
    sums[t] = s;
    __syncthreads();
    // Hillis-Steele inclusive scan over 1024 thread totals
    for (int off = 1; off < 1024; off <<= 1) {
        unsigned int v = (t >= off) ? sums[t - off] : 0u;
        __syncthreads();
        sums[t] += v;
        __syncthreads();
    }
    unsigned int run = sums[t] - s;  // exclusive prefix for this thread
#pragma unroll
    for (int j = 0; j < 8; ++j) {
        wordOffsets[8 * t + j] = run;
        run += c[j];
    }
    if (t == 1023) {
        *countp = run;                 // total active sites
        *out_count_f = (float)run;     // second output of the reference tuple
    }
}

// ---------------------------------------------------------------------------
// Kernel 3: gather/scatter of active rows. Block = 256 threads handles 256
// sites in 4 chunks of 64. Per chunk: stage [64 sites][64 ch] tile in LDS
// (stride 65 -> <=2-way bank aliasing on both sides), then 16 lanes per row
// emit one float4 each -> contiguous 256B per active row, consecutive rows
// contiguous in the compacted output.
// ---------------------------------------------------------------------------
__global__ __launch_bounds__(256) void k_scatter(const float* __restrict__ x,
                                                 const unsigned long long* __restrict__ flags,
                                                 const unsigned int* __restrict__ wordOffsets,
                                                 float* __restrict__ out) {
    __shared__ float tile[64 * 65];
    const int t = threadIdx.x;
    const int g = t >> 4;       // 0..15
    const int l16 = t & 15;     // 0..15

    for (int chunk = 0; chunk < 4; ++chunk) {
        const long long site0 = (long long)blockIdx.x * 256 + chunk * 64;
        const int wi = (int)(site0 >> 6);
        const unsigned long long wflag = flags[wi];
        const unsigned int woff = wordOffsets[wi];

        if (wflag != 0ull) {   // block-uniform: wi depends only on blockIdx/chunk
            // ---- stage: 4 iters, 16 channels each; thread loads float4 over sites
            const int b = (int)(site0 >> 14);
            const int hw0 = (int)(site0 & (HWSZ - 1)) + 4 * l16;
#pragma unroll
            for (int i = 0; i < 4; ++i) {
                const int c = g + 16 * i;
                const float4 v =
                    *reinterpret_cast<const float4*>(x + ((size_t)b * CC + c) * HWSZ + hw0);
                tile[(4 * l16 + 0) * 65 + c] = v.x;
                tile[(4 * l16 + 1) * 65 + c] = v.y;
                tile[(4 * l16 + 2) * 65 + c] = v.z;
                tile[(4 * l16 + 3) * 65 + c] = v.w;
            }
            __syncthreads();

            // ---- emit: group g handles rows g, g+16, g+32, g+48
#pragma unroll
            for (int i = 0; i < 4; ++i) {
                const int r = g + 16 * i;
                if ((wflag >> r) & 1ull) {
                    const unsigned long long before =
                        (r == 0) ? 0ull : (wflag & ((1ull << r) - 1ull));
                    const unsigned int pos = woff + (unsigned int)__popcll(before);
                    float4 v;
                    v.x = tile[r * 65 + 4 * l16 + 0];
                    v.y = tile[r * 65 + 4 * l16 + 1];
                    v.z = tile[r * 65 + 4 * l16 + 2];
                    v.w = tile[r * 65 + 4 * l16 + 3];
                    *reinterpret_cast<float4*>(out + (size_t)pos * CC + 4 * l16) = v;
                }
            }
            __syncthreads();
        }
    }
}

// ---------------------------------------------------------------------------
// Kernel 4: zero the padding rows [count, NSITES) of the output.
// ---------------------------------------------------------------------------
__global__ __launch_bounds__(256) void k_zero(float* __restrict__ out,
                                              const unsigned int* __restrict__ countp) {
    const unsigned int count = *countp;
    const size_t start4 = (size_t)count * (CC / 4);       // float4 index, exact
    const size_t n4 = (size_t)NSITES * (CC / 4);
    const size_t stride = (size_t)gridDim.x * blockDim.x;
    float4 z = make_float4(0.f, 0.f, 0.f, 0.f);
    for (size_t i = start4 + blockIdx.x * (size_t)blockDim.x + threadIdx.x; i < n4; i += stride)
        reinterpret_cast<float4*>(out)[i] = z;
}

extern "C" void kernel_launch(void* const* d_in, const int* in_sizes, int n_in,
                              void* d_out, int out_size, void* d_ws, size_t ws_size,
                              hipStream_t stream) {
    (void)in_sizes; (void)n_in; (void)out_size; (void)ws_size;
    const float* x = (const float*)d_in[0];
    float* out = (float*)d_out;

    char* ws = (char*)d_ws;
    unsigned long long* flags = (unsigned long long*)ws;                   // 64 KiB
    unsigned int* wordOffsets = (unsigned int*)(ws + 65536);               // 32 KiB
    unsigned int* countp = (unsigned int*)(ws + 65536 + 32768);            // 4 B

    float* out_count_f = out + (size_t)NSITES * CC;  // second tuple output

    hipLaunchKernelGGL(k_flags, dim3(NSITES / 1024), dim3(256), 0, stream, x, flags);
    hipLaunchKernelGGL(k_scan, dim3(1), dim3(1024), 0, stream, flags, wordOffsets, countp,
                       out_count_f);
    hipLaunchKernelGGL(k_scatter, dim3(NSITES / 256), dim3(256), 0, stream, x, flags,
                       wordOffsets, out);
    hipLaunchKernelGGL(k_zero, dim3(2048), dim3(256), 0, stream, out, countp);
}

// Round 4
// 70.791 us; speedup vs baseline: 1.0977x; 1.0977x over previous
//
#include <hip/hip_runtime.h>

// Problem constants
#define BB 32
#define CC 64
#define HH 128
#define WW 128
#define HWSZ (HH * WW)            // 16384
#define NSITES (BB * HWSZ)        // 524288
#define NWORDS (NSITES / 64)      // 8192

// native vector type: __builtin_nontemporal_store requires a scalar/vector
// (not HIP_vector_type class) pointee.
typedef float f32x4 __attribute__((ext_vector_type(4)));

// ---------------------------------------------------------------------------
// Kernel 1: per-site activity flags, packed 64 sites per uint64 word.
// Block = 256 threads handles 1024 consecutive sites (4 sites/thread, float4).
// Grid = 512 blocks. All loads coalesced: for fixed c, a wave reads 1 KiB
// contiguous.
// ---------------------------------------------------------------------------
__global__ __launch_bounds__(256) void k_flags(const float* __restrict__ x,
                                               unsigned long long* __restrict__ flags) {
    const int t = threadIdx.x;
    const long long site0 = (long long)blockIdx.x * 1024 + 4 * t;  // 4 consecutive sites
    const int b = (int)(site0 >> 14);       // /HWSZ  (blocks never straddle b)
    const int hw = (int)(site0 & (HWSZ - 1));
    const float* p = x + ((size_t)b * CC) * HWSZ + hw;

    float a0 = 0.f, a1 = 0.f, a2 = 0.f, a3 = 0.f;
#pragma unroll 8
    for (int c = 0; c < CC; ++c) {
        const f32x4 v = *reinterpret_cast<const f32x4*>(p + (size_t)c * HWSZ);
        a0 += fabsf(v.x);
        a1 += fabsf(v.y);
        a2 += fabsf(v.z);
        a3 += fabsf(v.w);
    }
    unsigned int nib = (unsigned int)(a0 != 0.f) | ((unsigned int)(a1 != 0.f) << 1) |
                       ((unsigned int)(a2 != 0.f) << 2) | ((unsigned int)(a3 != 0.f) << 3);

    __shared__ unsigned int nibs[256];
    nibs[t] = nib;
    __syncthreads();
    if (t < 16) {
        unsigned long long w = 0ull;
#pragma unroll
        for (int j = 0; j < 16; ++j)
            w |= (unsigned long long)nibs[16 * t + j] << (4 * j);
        flags[(size_t)blockIdx.x * 16 + t] = w;
    }
}

// ---------------------------------------------------------------------------
// Kernel 2: exclusive scan of per-word popcounts. Single block, 1024 threads,
// 8 words/thread. Also writes total count (uint in ws, float at end of d_out).
// ---------------------------------------------------------------------------
__global__ __launch_bounds__(1024) void k_scan(const unsigned long long* __restrict__ flags,
                                               unsigned int* __restrict__ wordOffsets,
                                               unsigned int* __restrict__ countp,
                                               float* __restrict__ out_count_f) {
    __shared__ unsigned int sums[1024];
    const int t = threadIdx.x;
    unsigned int c[8];
    unsigned int s = 0;
#pragma unroll
    for (int j = 0; j < 8; ++j) {
        c[j] = (unsigned int)__popcll(flags[8 * t + j]);
        s += c[j];
    }
    sums[t] = s;
    __syncthreads();
    // Hillis-Steele inclusive scan over 1024 thread totals
    for (int off = 1; off < 1024; off <<= 1) {
        unsigned int v = (t >= off) ? sums[t - off] : 0u;
        __syncthreads();
        sums[t] += v;
        __syncthreads();
    }
    unsigned int run = sums[t] - s;  // exclusive prefix for this thread
#pragma unroll
    for (int j = 0; j < 8; ++j) {
        wordOffsets[8 * t + j] = run;
        run += c[j];
    }
    if (t == 1023) {
        *countp = run;                 // total active sites
        *out_count_f = (float)run;     // second output of the reference tuple
    }
}

// ---------------------------------------------------------------------------
// Kernel 3: gather/scatter of ALL rows (active -> compacted front, inactive ->
// zero row in the padding region via the mirror map: the j-th inactive site in
// row-major order owns padding row NSITES-1-j). Every output row is written
// exactly once => no separate zero pass.
// Block = 256 threads handles 256 sites in 4 chunks of 64. Per chunk: stage
// [64 sites][64 ch] tile in LDS (stride 65 -> <=2-way bank aliasing, free on
// CDNA4), then 16 lanes per row emit one float4 each -> contiguous 256B rows.
// Output stores are non-temporal: d_out is write-only, keep L2/L3 for x.
// ---------------------------------------------------------------------------
__global__ __launch_bounds__(256) void k_scatter(const float* __restrict__ x,
                                                 const unsigned long long* __restrict__ flags,
                                                 const unsigned int* __restrict__ wordOffsets,
                                                 float* __restrict__ out) {
    __shared__ float tile[64 * 65];
    const int t = threadIdx.x;
    const int g = t >> 4;       // 0..15
    const int l16 = t & 15;     // 0..15

    for (int chunk = 0; chunk < 4; ++chunk) {
        const long long site0 = (long long)blockIdx.x * 256 + chunk * 64;
        const int wi = (int)(site0 >> 6);
        const unsigned long long wflag = flags[wi];
        const unsigned int woff = wordOffsets[wi];             // word's active offset
        const unsigned int iwoff = (unsigned int)wi * 64u - woff;  // word's inactive offset

        if (wflag != 0ull) {   // block-uniform: wi depends only on blockIdx/chunk
            // ---- stage: 4 iters, 16 channels each; thread loads float4 over sites
            const int b = (int)(site0 >> 14);
            const int hw0 = (int)(site0 & (HWSZ - 1)) + 4 * l16;
#pragma unroll
            for (int i = 0; i < 4; ++i) {
                const int c = g + 16 * i;
                const f32x4 v =
                    *reinterpret_cast<const f32x4*>(x + ((size_t)b * CC + c) * HWSZ + hw0);
                tile[(4 * l16 + 0) * 65 + c] = v.x;
                tile[(4 * l16 + 1) * 65 + c] = v.y;
                tile[(4 * l16 + 2) * 65 + c] = v.z;
                tile[(4 * l16 + 3) * 65 + c] = v.w;
            }
            __syncthreads();
        }

        // ---- emit: group g handles rows g, g+16, g+32, g+48 of this word
#pragma unroll
        for (int i = 0; i < 4; ++i) {
            const int r = g + 16 * i;
            const unsigned long long before = wflag & ((1ull << r) - 1ull);  // r==0 -> 0
            const unsigned int ab = (unsigned int)__popcll(before);
            if ((wflag >> r) & 1ull) {
                const unsigned int pos = woff + ab;
                f32x4 v;
                v.x = tile[r * 65 + 4 * l16 + 0];
                v.y = tile[r * 65 + 4 * l16 + 1];
                v.z = tile[r * 65 + 4 * l16 + 2];
                v.w = tile[r * 65 + 4 * l16 + 3];
                __builtin_nontemporal_store(
                    v, reinterpret_cast<f32x4*>(out + (size_t)pos * CC + 4 * l16));
            } else {
                const unsigned int ipos = iwoff + ((unsigned int)r - ab);
                const size_t zrow = (size_t)(NSITES - 1) - ipos;
                const f32x4 z = {0.f, 0.f, 0.f, 0.f};
                __builtin_nontemporal_store(
                    z, reinterpret_cast<f32x4*>(out + zrow * CC + 4 * l16));
            }
        }

        if (wflag != 0ull) __syncthreads();  // protect tile before next chunk's staging
    }
}

extern "C" void kernel_launch(void* const* d_in, const int* in_sizes, int n_in,
                              void* d_out, int out_size, void* d_ws, size_t ws_size,
                              hipStream_t stream) {
    (void)in_sizes; (void)n_in; (void)out_size; (void)ws_size;
    const float* x = (const float*)d_in[0];
    float* out = (float*)d_out;

    char* ws = (char*)d_ws;
    unsigned long long* flags = (unsigned long long*)ws;                   // 64 KiB
    unsigned int* wordOffsets = (unsigned int*)(ws + 65536);               // 32 KiB
    unsigned int* countp = (unsigned int*)(ws + 65536 + 32768);            // 4 B

    float* out_count_f = out + (size_t)NSITES * CC;  // second tuple output

    hipLaunchKernelGGL(k_flags, dim3(NSITES / 1024), dim3(256), 0, stream, x, flags);
    hipLaunchKernelGGL(k_scan, dim3(1), dim3(1024), 0, stream, flags, wordOffsets, countp,
                       out_count_f);
    hipLaunchKernelGGL(k_scatter, dim3(NSITES / 256), dim3(256), 0, stream, x, flags,
                       wordOffsets, out);
}